// Round 2
// baseline (452.273 us; speedup 1.0000x reference)
//
#include <hip/hip_runtime.h>

// Deformable 2x bilinear upsample.
// input:  (B=8, C=128, H=128, W=128) fp32
// offset_x/offset_y: (B, 1, Ho=256, Wo=256) fp32
// out:    (B, C, Ho, Wo) fp32
//
// R2: one thread = one output pixel; a wave's 64 lanes cover 64 consecutive
// wo so each gather instruction touches ~2-3 cache lines in x (instead of 8
// when lanes were 4-apart). Coordinates shared across channels: compute
// indices/weights once, loop 32 channels per thread (grid.z = 4 groups).

constexpr int B  = 8;
constexpr int C  = 128;
constexpr int H  = 128;
constexpr int W  = 128;
constexpr int Ho = 256;
constexpr int Wo = 256;
constexpr int HW = H * W;        // 16384
constexpr int CG  = 4;           // channel groups (grid.z)
constexpr int CPG = C / CG;      // 32 channels per thread

__global__ __launch_bounds__(256) void deform_upsample_kernel(
    const float* __restrict__ in,
    const float* __restrict__ offx,
    const float* __restrict__ offy,
    float* __restrict__ out)
{
    const int wo = threadIdx.x;        // 0..255, lane i -> consecutive wo
    const int ho = blockIdx.x;         // 0..255
    const int b  = blockIdx.y;
    const int c0 = blockIdx.z * CPG;

    // Offsets: shape (B,1,Ho,Wo) — coalesced 4B/lane
    const int s = (b * Ho + ho) * Wo + wo;
    const float x = (float)wo * 0.5f + offx[s];
    const float y = (float)ho * 0.5f + offy[s];

    const float y0f = floorf(y);
    const float x0f = floorf(x);
    const float wy = y - y0f;
    const float wx = x - x0f;
    const int y0 = (int)y0f;
    const int x0 = (int)x0f;
    const int y1 = y0 + 1;
    const int x1 = x0 + 1;

    const bool vy0 = ((unsigned)y0 < (unsigned)H);
    const bool vy1 = ((unsigned)y1 < (unsigned)H);
    const bool vx0 = ((unsigned)x0 < (unsigned)W);
    const bool vx1 = ((unsigned)x1 < (unsigned)W);

    const int yc0 = min(max(y0, 0), H - 1);
    const int yc1 = min(max(y1, 0), H - 1);
    const int xc0 = min(max(x0, 0), W - 1);
    const int xc1 = min(max(x1, 0), W - 1);

    const int i00 = yc0 * W + xc0;
    const int i01 = yc0 * W + xc1;
    const int i10 = yc1 * W + xc0;
    const int i11 = yc1 * W + xc1;

    const float omwy = 1.0f - wy;
    const float omwx = 1.0f - wx;
    const float w00 = (vy0 && vx0) ? (omwy * omwx) : 0.0f;
    const float w01 = (vy0 && vx1) ? (omwy * wx)   : 0.0f;
    const float w10 = (vy1 && vx0) ? (wy   * omwx) : 0.0f;
    const float w11 = (vy1 && vx1) ? (wy   * wx)   : 0.0f;

    const float* ip = in  + (size_t)(b * C + c0) * HW;
    float*       op = out + ((size_t)(b * C + c0) * Ho + ho) * Wo + wo;

#pragma unroll 8
    for (int c = 0; c < CPG; ++c) {
        float acc;
        acc = w00 * ip[i00];
        acc = fmaf(w01, ip[i01], acc);
        acc = fmaf(w10, ip[i10], acc);
        acc = fmaf(w11, ip[i11], acc);
        *op = acc;
        ip += HW;
        op += (size_t)Ho * Wo;
    }
}

extern "C" void kernel_launch(void* const* d_in, const int* in_sizes, int n_in,
                              void* d_out, int out_size, void* d_ws, size_t ws_size,
                              hipStream_t stream) {
    const float* in   = (const float*)d_in[0];
    const float* offx = (const float*)d_in[1];
    const float* offy = (const float*)d_in[2];
    float* out = (float*)d_out;

    dim3 grid(Ho, B, CG);   // 256 x 8 x 4 = 8192 blocks
    dim3 block(256);        // one full output row per block
    deform_upsample_kernel<<<grid, block, 0, stream>>>(in, offx, offy, out);
}